// Round 4
// baseline (196.274 us; speedup 1.0000x reference)
//
#include <hip/hip_runtime.h>
#include <math.h>

#define NROWS 1546
#define INDIM 1546
#define ODIM  64
#define NDRUG 1373
#define MINN  1e-15f
#define MAXNRM 0.996f   // (1 - 4e-3)/sqrt(c), c=1

#define KS   8          // K-splits (blocks in y)
#define CH   194        // K-chunk per split (8*194 >= 1546)
#define RSTR 196        // LDS row stride in floats (196*4 % 16 == 0)
#define NRG  194        // row-groups of 8

__device__ __forceinline__ float artanh_(float x) {
    x = fminf(fmaxf(x, -1.0f + 1e-7f), 1.0f - 1e-7f);
    return 0.5f * (log1pf(x) - log1pf(-x));
}

__device__ __forceinline__ float wsum(float v) {
#pragma unroll
    for (int off = 32; off > 0; off >>= 1) v += __shfl_xor(v, off, 64);
    return v;
}

// ---- kernel 1: transpose W (blocks 0..N-2), bias prep + counter zero (last block) ----
__global__ void prep_kernel(const float* __restrict__ Wd, const float* __restrict__ Wm,
                            float* __restrict__ WtD, float* __restrict__ WtM,
                            const float* __restrict__ bd, const float* __restrict__ bm,
                            float* __restrict__ hbD, float* __restrict__ hbM,
                            float* __restrict__ hb2, unsigned* __restrict__ cnt /*2*NRG*/) {
    if (blockIdx.x == gridDim.x - 1) {
        int tid = threadIdx.x;
        for (int i = tid; i < 2 * NRG; i += blockDim.x) cnt[i] = 0u;
        if (tid < 128) {
            int wave = tid >> 6, lane = tid & 63;
            const float* b = wave ? bm : bd;
            float v = b[lane];
            float un2 = wsum(v * v);
            float un = fmaxf(sqrtf(un2), MINN);
            float e = tanhf(un) * v / un;
            float en2 = wsum(e * e);
            float en = fmaxf(sqrtf(en2), MINN);
            float scl = (en > MAXNRM) ? (MAXNRM / en) : 1.0f;
            e *= scl;
            float* hb = wave ? hbM : hbD;
            hb[lane] = e;
            if (lane == 0) hb2[wave] = en2 * scl * scl;
        }
        return;
    }
    int nblk = gridDim.x - 1;
    int total = ODIM * INDIM;
    for (int i = blockIdx.x * blockDim.x + threadIdx.x; i < total; i += nblk * blockDim.x) {
        int o = i / INDIM;
        int k = i - o * INDIM;
        WtD[k * ODIM + o] = Wd[i];
        WtM[k * ODIM + o] = Wm[i];
    }
}

// ---- kernel 2: split-K x@Wt, last block per row-group reduces + hyperbolic epilogue ----
__global__ __launch_bounds__(256) void gemm_liner_fused(
    const float* __restrict__ X, const float* __restrict__ WtD, const float* __restrict__ WtM,
    const float* __restrict__ hbD, const float* __restrict__ hbM, const float* __restrict__ hb2v,
    float* __restrict__ part, float* __restrict__ pnorm, unsigned* __restrict__ cnt,
    float* __restrict__ liner, float* __restrict__ xtan) {
    __shared__ __align__(16) float xs[8 * RSTR];
    __shared__ unsigned last_flag;
    int tid = threadIdx.x, wave = tid >> 6, lane = tid & 63;
    int row0 = blockIdx.x * 8;
    int kc = blockIdx.y;
    int k0 = kc * CH;
    int len = min(INDIM - k0, CH);

    {   // stage 8 rows x len as float2 (32 threads per row)
        int r = tid >> 5, c0 = tid & 31;
        int gr = min(row0 + r, NROWS - 1);
        const float2* src = (const float2*)(X + (size_t)gr * INDIM + k0);
        float2* dst = (float2*)&xs[r * RSTR];
        int len2 = len >> 1;
        for (int c = c0; c < len2; c += 32) dst[c] = src[c];
    }
    __syncthreads();

    int r0 = 2 * wave, r1 = r0 + 1;
    int g0 = row0 + r0, g1 = g0 + 1;

    {   // partial squared norms
        float p0 = 0.f, p1 = 0.f;
        for (int c = lane; c < len; c += 64) {
            float a = xs[r0 * RSTR + c]; p0 = fmaf(a, a, p0);
            float b = xs[r1 * RSTR + c]; p1 = fmaf(b, b, p1);
        }
        p0 = wsum(p0); p1 = wsum(p1);
        if (lane == 0) {
            if (g0 < NROWS) pnorm[g0 * KS + kc] = p0;
            if (g1 < NROWS) pnorm[g1 * KS + kc] = p1;
        }
    }

    float acc0 = 0.f, acc1 = 0.f;
    bool u = (g0 < NDRUG) == (g1 < NDRUG);
    if (u) {
        const float* wp = ((g0 < NDRUG) ? WtD : WtM) + (size_t)k0 * 64 + lane;
        int kk = 0;
        for (; kk + 4 <= len; kk += 4) {
            float w0 = wp[(kk + 0) * 64];
            float w1 = wp[(kk + 1) * 64];
            float w2 = wp[(kk + 2) * 64];
            float w3 = wp[(kk + 3) * 64];
            float4 a = *(const float4*)(xs + r0 * RSTR + kk);
            float4 b = *(const float4*)(xs + r1 * RSTR + kk);
            acc0 = fmaf(a.x, w0, acc0); acc0 = fmaf(a.y, w1, acc0);
            acc0 = fmaf(a.z, w2, acc0); acc0 = fmaf(a.w, w3, acc0);
            acc1 = fmaf(b.x, w0, acc1); acc1 = fmaf(b.y, w1, acc1);
            acc1 = fmaf(b.z, w2, acc1); acc1 = fmaf(b.w, w3, acc1);
        }
        for (; kk < len; ++kk) {
            float w = wp[kk * 64];
            acc0 = fmaf(xs[r0 * RSTR + kk], w, acc0);
            acc1 = fmaf(xs[r1 * RSTR + kk], w, acc1);
        }
    } else {
        const float* wp0 = ((g0 < NDRUG) ? WtD : WtM) + (size_t)k0 * 64 + lane;
        const float* wp1 = ((g1 < NDRUG) ? WtD : WtM) + (size_t)k0 * 64 + lane;
        for (int kk = 0; kk < len; ++kk) {
            acc0 = fmaf(xs[r0 * RSTR + kk], wp0[kk * 64], acc0);
            acc1 = fmaf(xs[r1 * RSTR + kk], wp1[kk * 64], acc1);
        }
    }
    if (g0 < NROWS) part[(size_t)g0 * (KS * 64) + kc * 64 + lane] = acc0;
    if (g1 < NROWS) part[(size_t)g1 * (KS * 64) + kc * 64 + lane] = acc1;

    // ---- split-K completion: last block per row-group reduces + epilogue ----
    __syncthreads();
    if (tid == 0) {
        __builtin_amdgcn_fence(__ATOMIC_RELEASE, "agent");
        unsigned prev = __hip_atomic_fetch_add(&cnt[blockIdx.x], 1u,
                                               __ATOMIC_ACQ_REL, __HIP_MEMORY_SCOPE_AGENT);
        last_flag = (prev == KS - 1) ? 1u : 0u;
    }
    __syncthreads();
    if (!last_flag) return;
    __builtin_amdgcn_fence(__ATOMIC_ACQUIRE, "agent");

#pragma unroll
    for (int j = 0; j < 2; ++j) {
        int grow = row0 + wave + 4 * j;
        if (grow < NROWS) {
            float mx = 0.f, xn2 = 0.f;
#pragma unroll
            for (int k = 0; k < KS; ++k) mx += part[(size_t)grow * (KS * 64) + k * 64 + lane];
#pragma unroll
            for (int k = 0; k < KS; ++k) xn2 += pnorm[grow * KS + k];
            float mxn2 = wsum(mx * mx);
            float xn = fmaxf(sqrtf(xn2), MINN);
            float mxn = fmaxf(sqrtf(mxn2), MINN);
            float g = mxn / xn * artanh_(xn);
            float t = tanhf(g);
            float res = t * mx / mxn;          // |res| == |t|
            float rn = fabsf(t);
            if (rn > MAXNRM) { res *= MAXNRM / rn; rn = MAXNRM; }
            const float* hb = (grow < NDRUG) ? hbD : hbM;
            float y = hb[lane];
            float y2 = hb2v[(grow < NDRUG) ? 0 : 1];
            float x2 = rn * rn;
            float xy = wsum(res * y);
            float num = (1.0f + 2.0f * xy + y2) * res + (1.0f - x2) * y;
            float den = 1.0f + 2.0f * xy + x2 * y2;
            float v = num / fmaxf(den, MINN);
            float v2 = wsum(v * v);
            float vn = fmaxf(sqrtf(v2), MINN);
            if (vn > MAXNRM) { v *= MAXNRM / vn; vn = MAXNRM; }
            float xt = artanh_(vn) / vn * v;   // logmap0
            liner[(size_t)grow * ODIM + lane] = v;
            xtan[(size_t)grow * ODIM + lane] = xt;
        }
    }
    if (tid == 0)
        __hip_atomic_store(&cnt[blockIdx.x], 0u, __ATOMIC_RELAXED, __HIP_MEMORY_SCOPE_AGENT);
}

// ---- kernel 3: split-K adj@xtan (+adj copy), last block reduces + HypAct -> h ----
__global__ __launch_bounds__(256) void gemm_agg_fused(
    const float* __restrict__ ADJ, const float* __restrict__ xtan,
    const float* __restrict__ liner, const float* __restrict__ WN /*[128][64]*/,
    const float* __restrict__ biasnode, float* __restrict__ part,
    unsigned* __restrict__ cnt, float* __restrict__ out_h,
    float* __restrict__ adj_out, int fuse_copy) {
    __shared__ __align__(16) float xs[8 * RSTR];
    __shared__ float zl[8][128];
    __shared__ unsigned last_flag;
    int tid = threadIdx.x, wave = tid >> 6, lane = tid & 63;
    int row0 = blockIdx.x * 8;
    int kc = blockIdx.y;
    int k0 = kc * CH;
    int len = min(INDIM - k0, CH);

    {   // stage 8 rows x len as float2; optionally also write adj copy
        int r = tid >> 5, c0 = tid & 31;
        int gr0 = row0 + r;
        int gr = min(gr0, NROWS - 1);
        const float2* src = (const float2*)(ADJ + (size_t)gr * INDIM + k0);
        float2* dst = (float2*)&xs[r * RSTR];
        int len2 = len >> 1;
        if (fuse_copy && gr0 < NROWS) {
            float2* cp = (float2*)(adj_out + (size_t)gr0 * INDIM + k0);
            for (int c = c0; c < len2; c += 32) { float2 v = src[c]; dst[c] = v; cp[c] = v; }
        } else {
            for (int c = c0; c < len2; c += 32) dst[c] = src[c];
        }
    }
    __syncthreads();

    int r0 = 2 * wave, r1 = r0 + 1;
    int g0 = row0 + r0, g1 = g0 + 1;

    float acc0 = 0.f, acc1 = 0.f;
    {
        const float* wp = xtan + (size_t)k0 * 64 + lane;
        int kk = 0;
        for (; kk + 4 <= len; kk += 4) {
            float w0 = wp[(kk + 0) * 64];
            float w1 = wp[(kk + 1) * 64];
            float w2 = wp[(kk + 2) * 64];
            float w3 = wp[(kk + 3) * 64];
            float4 a = *(const float4*)(xs + r0 * RSTR + kk);
            float4 b = *(const float4*)(xs + r1 * RSTR + kk);
            acc0 = fmaf(a.x, w0, acc0); acc0 = fmaf(a.y, w1, acc0);
            acc0 = fmaf(a.z, w2, acc0); acc0 = fmaf(a.w, w3, acc0);
            acc1 = fmaf(b.x, w0, acc1); acc1 = fmaf(b.y, w1, acc1);
            acc1 = fmaf(b.z, w2, acc1); acc1 = fmaf(b.w, w3, acc1);
        }
        for (; kk < len; ++kk) {
            float w = wp[kk * 64];
            acc0 = fmaf(xs[r0 * RSTR + kk], w, acc0);
            acc1 = fmaf(xs[r1 * RSTR + kk], w, acc1);
        }
    }
    if (g0 < NROWS) part[(size_t)g0 * (KS * 64) + kc * 64 + lane] = acc0;
    if (g1 < NROWS) part[(size_t)g1 * (KS * 64) + kc * 64 + lane] = acc1;

    __syncthreads();
    if (tid == 0) {
        __builtin_amdgcn_fence(__ATOMIC_RELEASE, "agent");
        unsigned prev = __hip_atomic_fetch_add(&cnt[blockIdx.x], 1u,
                                               __ATOMIC_ACQ_REL, __HIP_MEMORY_SCOPE_AGENT);
        last_flag = (prev == KS - 1) ? 1u : 0u;
    }
    __syncthreads();
    if (!last_flag) return;
    __builtin_amdgcn_fence(__ATOMIC_ACQUIRE, "agent");

#pragma unroll
    for (int j = 0; j < 2; ++j) {
        int r = wave + 4 * j;
        int grow = row0 + r;
        if (grow < NROWS) {
            float s = 0.f;
#pragma unroll
            for (int k = 0; k < KS; ++k) s += part[(size_t)grow * (KS * 64) + k * 64 + lane];
            float sn2 = wsum(s * s);
            float sn = fmaxf(sqrtf(sn2), MINN);
            float th = tanhf(sn);
            float agg = th * s / sn;           // expmap0; |agg| == th
            if (th > MAXNRM) agg *= MAXNRM / th;
            float lin = liner[(size_t)grow * ODIM + lane];
            zl[r][lane] = agg;
            zl[r][64 + lane] = lin;            // same-wave LDS RAW, no barrier needed
            float d = biasnode[grow];
            const float* w = WN + lane;
#pragma unroll 8
            for (int f = 0; f < 128; ++f) d = fmaf(zl[r][f], w[f * 64], d);
            d = fmaxf(d, 0.0f);
            out_h[(size_t)grow * ODIM + lane] = d * agg + (1.0f - d) * lin;
        }
    }
    if (tid == 0)
        __hip_atomic_store(&cnt[blockIdx.x], 0u, __ATOMIC_RELAXED, __HIP_MEMORY_SCOPE_AGENT);
}

// ---- fallback: copy adj into second tuple output ----
__global__ void copy_adj(const float4* __restrict__ src, float4* __restrict__ dst, int n4) {
    for (int i = blockIdx.x * blockDim.x + threadIdx.x; i < n4; i += gridDim.x * blockDim.x)
        dst[i] = src[i];
}

extern "C" void kernel_launch(void* const* d_in, const int* in_sizes, int n_in,
                              void* d_out, int out_size, void* d_ws, size_t ws_size,
                              hipStream_t stream) {
    const float* x   = (const float*)d_in[0];
    const float* adj = (const float*)d_in[1];
    const float* Wd  = (const float*)d_in[2];
    const float* Wm  = (const float*)d_in[3];
    const float* bd  = (const float*)d_in[4];
    const float* bm  = (const float*)d_in[5];
    const float* wn  = (const float*)d_in[6];
    const float* bn  = (const float*)d_in[7];
    float* out = (float*)d_out;
    float* ws  = (float*)d_ws;

    const int WELEMS = ODIM * INDIM;          // 98944
    float* WtD   = ws;                        // 98944
    float* WtM   = ws + WELEMS;               // 98944
    float* hbD   = ws + 2 * WELEMS;           // 64
    float* hbM   = hbD + 64;                  // 64
    float* hb2   = hbM + 64;                  // 2
    float* liner = ws + 2 * WELEMS + 192;     // 98944
    float* xtan  = liner + WELEMS;            // 98944
    float* pnorm = xtan + WELEMS;             // 1546*8 = 12368
    unsigned* cnt = (unsigned*)(pnorm + 12368); // 2*194
    float* ws_end = (float*)(cnt + 2 * NRG);
    size_t used = (size_t)(ws_end - ws);
    // part: 1546*8*64 = 791552 floats, 64-float aligned
    size_t part_off = (used + 63) & ~(size_t)63;
    size_t need = (part_off + (size_t)NROWS * KS * 64) * sizeof(float);
    int fast = (ws_size >= need);
    float* part = fast ? (ws + part_off) : (out + WELEMS);

    unsigned* cntL = cnt;
    unsigned* cntA = cnt + NRG;

    prep_kernel<<<388, 256, 0, stream>>>(Wd, Wm, WtD, WtM, bd, bm, hbD, hbM, hb2, cnt);

    dim3 gA(NRG, KS);
    gemm_liner_fused<<<gA, 256, 0, stream>>>(x, WtD, WtM, hbD, hbM, hb2,
                                             part, pnorm, cntL, liner, xtan);
    gemm_agg_fused<<<gA, 256, 0, stream>>>(adj, xtan, liner, wn, bn,
                                           part, cntA, out, out + WELEMS, fast);
    if (!fast) {
        int n4 = (NROWS * NROWS) / 4;
        copy_adj<<<(n4 + 255) / 256, 256, 0, stream>>>((const float4*)adj,
                                                       (float4*)(out + WELEMS), n4);
    }
}

// Round 5
// 196.081 us; speedup vs baseline: 1.0010x; 1.0010x over previous
//
#include <hip/hip_runtime.h>
#include <math.h>

#define NROWS 1546
#define INDIM 1546
#define ODIM  64
#define NDRUG 1373
#define MINN  1e-15f
#define MAXNRM 0.996f   // (1 - 4e-3)/sqrt(c), c=1

#define KS   8          // K-splits (blocks in y)
#define CH   194        // K-chunk per split (8*194 >= 1546)
#define RSTR 196        // LDS row stride in floats (196*4 % 16 == 0)
#define NRG  194        // row-groups of 8

__device__ __forceinline__ float artanh_(float x) {
    x = fminf(fmaxf(x, -1.0f + 1e-7f), 1.0f - 1e-7f);
    return 0.5f * (log1pf(x) - log1pf(-x));
}

__device__ __forceinline__ float wsum(float v) {
#pragma unroll
    for (int off = 32; off > 0; off >>= 1) v += __shfl_xor(v, off, 64);
    return v;
}

// ---- kernel 1: transpose W (blocks 0..N-2), bias prep + counter zero (last block) ----
__global__ void prep_kernel(const float* __restrict__ Wd, const float* __restrict__ Wm,
                            float* __restrict__ WtD, float* __restrict__ WtM,
                            const float* __restrict__ bd, const float* __restrict__ bm,
                            float* __restrict__ hbD, float* __restrict__ hbM,
                            float* __restrict__ hb2, unsigned* __restrict__ cnt /*2*NRG*/) {
    if (blockIdx.x == gridDim.x - 1) {
        int tid = threadIdx.x;
        for (int i = tid; i < 2 * NRG; i += blockDim.x) cnt[i] = 0u;
        if (tid < 128) {
            int wave = tid >> 6, lane = tid & 63;
            const float* b = wave ? bm : bd;
            float v = b[lane];
            float un2 = wsum(v * v);
            float un = fmaxf(sqrtf(un2), MINN);
            float e = tanhf(un) * v / un;
            float en2 = wsum(e * e);
            float en = fmaxf(sqrtf(en2), MINN);
            float scl = (en > MAXNRM) ? (MAXNRM / en) : 1.0f;
            e *= scl;
            float* hb = wave ? hbM : hbD;
            hb[lane] = e;
            if (lane == 0) hb2[wave] = en2 * scl * scl;
        }
        return;
    }
    int nblk = gridDim.x - 1;
    int total = ODIM * INDIM;
    for (int i = blockIdx.x * blockDim.x + threadIdx.x; i < total; i += nblk * blockDim.x) {
        int o = i / INDIM;
        int k = i - o * INDIM;
        WtD[k * ODIM + o] = Wd[i];
        WtM[k * ODIM + o] = Wm[i];
    }
}

// ---- kernel 2: split-K x@Wt, last block per row-group reduces + hyperbolic epilogue ----
__global__ __launch_bounds__(256) void gemm_liner_fused(
    const float* __restrict__ X, const float* __restrict__ WtD, const float* __restrict__ WtM,
    const float* __restrict__ hbD, const float* __restrict__ hbM, const float* __restrict__ hb2v,
    float* __restrict__ part, float* __restrict__ pnorm, unsigned* __restrict__ cnt,
    float* __restrict__ liner, float* __restrict__ xtan) {
    __shared__ __align__(16) float xs[8 * RSTR];
    __shared__ unsigned last_flag;
    int tid = threadIdx.x, wave = tid >> 6, lane = tid & 63;
    int row0 = blockIdx.x * 8;
    int kc = blockIdx.y;
    int k0 = kc * CH;
    int len = min(INDIM - k0, CH);

    {   // stage 8 rows x len as float2 (32 threads per row)
        int r = tid >> 5, c0 = tid & 31;
        int gr = min(row0 + r, NROWS - 1);
        const float2* src = (const float2*)(X + (size_t)gr * INDIM + k0);
        float2* dst = (float2*)&xs[r * RSTR];
        int len2 = len >> 1;
        for (int c = c0; c < len2; c += 32) dst[c] = src[c];
    }
    __syncthreads();

    int r0 = 2 * wave, r1 = r0 + 1;
    int g0 = row0 + r0, g1 = g0 + 1;

    {   // partial squared norms
        float p0 = 0.f, p1 = 0.f;
        for (int c = lane; c < len; c += 64) {
            float a = xs[r0 * RSTR + c]; p0 = fmaf(a, a, p0);
            float b = xs[r1 * RSTR + c]; p1 = fmaf(b, b, p1);
        }
        p0 = wsum(p0); p1 = wsum(p1);
        if (lane == 0) {
            if (g0 < NROWS) pnorm[g0 * KS + kc] = p0;
            if (g1 < NROWS) pnorm[g1 * KS + kc] = p1;
        }
    }

    float acc0 = 0.f, acc1 = 0.f;
    bool u = (g0 < NDRUG) == (g1 < NDRUG);
    if (u) {
        const float* wp = ((g0 < NDRUG) ? WtD : WtM) + (size_t)k0 * 64 + lane;
        int kk = 0;
        for (; kk + 4 <= len; kk += 4) {
            float w0 = wp[(kk + 0) * 64];
            float w1 = wp[(kk + 1) * 64];
            float w2 = wp[(kk + 2) * 64];
            float w3 = wp[(kk + 3) * 64];
            float4 a = *(const float4*)(xs + r0 * RSTR + kk);
            float4 b = *(const float4*)(xs + r1 * RSTR + kk);
            acc0 = fmaf(a.x, w0, acc0); acc0 = fmaf(a.y, w1, acc0);
            acc0 = fmaf(a.z, w2, acc0); acc0 = fmaf(a.w, w3, acc0);
            acc1 = fmaf(b.x, w0, acc1); acc1 = fmaf(b.y, w1, acc1);
            acc1 = fmaf(b.z, w2, acc1); acc1 = fmaf(b.w, w3, acc1);
        }
        for (; kk < len; ++kk) {
            float w = wp[kk * 64];
            acc0 = fmaf(xs[r0 * RSTR + kk], w, acc0);
            acc1 = fmaf(xs[r1 * RSTR + kk], w, acc1);
        }
    } else {
        const float* wp0 = ((g0 < NDRUG) ? WtD : WtM) + (size_t)k0 * 64 + lane;
        const float* wp1 = ((g1 < NDRUG) ? WtD : WtM) + (size_t)k0 * 64 + lane;
        for (int kk = 0; kk < len; ++kk) {
            acc0 = fmaf(xs[r0 * RSTR + kk], wp0[kk * 64], acc0);
            acc1 = fmaf(xs[r1 * RSTR + kk], wp1[kk * 64], acc1);
        }
    }
    if (g0 < NROWS) part[(size_t)g0 * (KS * 64) + kc * 64 + lane] = acc0;
    if (g1 < NROWS) part[(size_t)g1 * (KS * 64) + kc * 64 + lane] = acc1;

    // ---- split-K completion: last block per row-group reduces + epilogue ----
    __syncthreads();
    if (tid == 0) {
        __builtin_amdgcn_fence(__ATOMIC_RELEASE, "agent");
        unsigned prev = __hip_atomic_fetch_add(&cnt[blockIdx.x], 1u,
                                               __ATOMIC_ACQ_REL, __HIP_MEMORY_SCOPE_AGENT);
        last_flag = (prev == KS - 1) ? 1u : 0u;
    }
    __syncthreads();
    if (!last_flag) return;
    __builtin_amdgcn_fence(__ATOMIC_ACQUIRE, "agent");

#pragma unroll
    for (int j = 0; j < 2; ++j) {
        int grow = row0 + wave + 4 * j;
        if (grow < NROWS) {
            float mx = 0.f, xn2 = 0.f;
#pragma unroll
            for (int k = 0; k < KS; ++k) mx += part[(size_t)grow * (KS * 64) + k * 64 + lane];
#pragma unroll
            for (int k = 0; k < KS; ++k) xn2 += pnorm[grow * KS + k];
            float mxn2 = wsum(mx * mx);
            float xn = fmaxf(sqrtf(xn2), MINN);
            float mxn = fmaxf(sqrtf(mxn2), MINN);
            float g = mxn / xn * artanh_(xn);
            float t = tanhf(g);
            float res = t * mx / mxn;          // |res| == |t|
            float rn = fabsf(t);
            if (rn > MAXNRM) { res *= MAXNRM / rn; rn = MAXNRM; }
            const float* hb = (grow < NDRUG) ? hbD : hbM;
            float y = hb[lane];
            float y2 = hb2v[(grow < NDRUG) ? 0 : 1];
            float x2 = rn * rn;
            float xy = wsum(res * y);
            float num = (1.0f + 2.0f * xy + y2) * res + (1.0f - x2) * y;
            float den = 1.0f + 2.0f * xy + x2 * y2;
            float v = num / fmaxf(den, MINN);
            float v2 = wsum(v * v);
            float vn = fmaxf(sqrtf(v2), MINN);
            if (vn > MAXNRM) { v *= MAXNRM / vn; vn = MAXNRM; }
            float xt = artanh_(vn) / vn * v;   // logmap0
            liner[(size_t)grow * ODIM + lane] = v;
            xtan[(size_t)grow * ODIM + lane] = xt;
        }
    }
    if (tid == 0)
        __hip_atomic_store(&cnt[blockIdx.x], 0u, __ATOMIC_RELAXED, __HIP_MEMORY_SCOPE_AGENT);
}

// ---- kernel 3: split-K adj@xtan (+adj copy), last block reduces + HypAct -> h ----
__global__ __launch_bounds__(256) void gemm_agg_fused(
    const float* __restrict__ ADJ, const float* __restrict__ xtan,
    const float* __restrict__ liner, const float* __restrict__ WN /*[128][64]*/,
    const float* __restrict__ biasnode, float* __restrict__ part,
    unsigned* __restrict__ cnt, float* __restrict__ out_h,
    float* __restrict__ adj_out, int fuse_copy) {
    __shared__ __align__(16) float xs[8 * RSTR];
    __shared__ float zl[8][128];
    __shared__ unsigned last_flag;
    int tid = threadIdx.x, wave = tid >> 6, lane = tid & 63;
    int row0 = blockIdx.x * 8;
    int kc = blockIdx.y;
    int k0 = kc * CH;
    int len = min(INDIM - k0, CH);

    {   // stage 8 rows x len as float2; optionally also write adj copy
        int r = tid >> 5, c0 = tid & 31;
        int gr0 = row0 + r;
        int gr = min(gr0, NROWS - 1);
        const float2* src = (const float2*)(ADJ + (size_t)gr * INDIM + k0);
        float2* dst = (float2*)&xs[r * RSTR];
        int len2 = len >> 1;
        if (fuse_copy && gr0 < NROWS) {
            float2* cp = (float2*)(adj_out + (size_t)gr0 * INDIM + k0);
            for (int c = c0; c < len2; c += 32) { float2 v = src[c]; dst[c] = v; cp[c] = v; }
        } else {
            for (int c = c0; c < len2; c += 32) dst[c] = src[c];
        }
    }
    __syncthreads();

    int r0 = 2 * wave, r1 = r0 + 1;
    int g0 = row0 + r0, g1 = g0 + 1;

    float acc0 = 0.f, acc1 = 0.f;
    {
        const float* wp = xtan + (size_t)k0 * 64 + lane;
        int kk = 0;
        for (; kk + 4 <= len; kk += 4) {
            float w0 = wp[(kk + 0) * 64];
            float w1 = wp[(kk + 1) * 64];
            float w2 = wp[(kk + 2) * 64];
            float w3 = wp[(kk + 3) * 64];
            float4 a = *(const float4*)(xs + r0 * RSTR + kk);
            float4 b = *(const float4*)(xs + r1 * RSTR + kk);
            acc0 = fmaf(a.x, w0, acc0); acc0 = fmaf(a.y, w1, acc0);
            acc0 = fmaf(a.z, w2, acc0); acc0 = fmaf(a.w, w3, acc0);
            acc1 = fmaf(b.x, w0, acc1); acc1 = fmaf(b.y, w1, acc1);
            acc1 = fmaf(b.z, w2, acc1); acc1 = fmaf(b.w, w3, acc1);
        }
        for (; kk < len; ++kk) {
            float w = wp[kk * 64];
            acc0 = fmaf(xs[r0 * RSTR + kk], w, acc0);
            acc1 = fmaf(xs[r1 * RSTR + kk], w, acc1);
        }
    }
    if (g0 < NROWS) part[(size_t)g0 * (KS * 64) + kc * 64 + lane] = acc0;
    if (g1 < NROWS) part[(size_t)g1 * (KS * 64) + kc * 64 + lane] = acc1;

    __syncthreads();
    if (tid == 0) {
        __builtin_amdgcn_fence(__ATOMIC_RELEASE, "agent");
        unsigned prev = __hip_atomic_fetch_add(&cnt[blockIdx.x], 1u,
                                               __ATOMIC_ACQ_REL, __HIP_MEMORY_SCOPE_AGENT);
        last_flag = (prev == KS - 1) ? 1u : 0u;
    }
    __syncthreads();
    if (!last_flag) return;
    __builtin_amdgcn_fence(__ATOMIC_ACQUIRE, "agent");

#pragma unroll
    for (int j = 0; j < 2; ++j) {
        int r = wave + 4 * j;
        int grow = row0 + r;
        if (grow < NROWS) {
            float s = 0.f;
#pragma unroll
            for (int k = 0; k < KS; ++k) s += part[(size_t)grow * (KS * 64) + k * 64 + lane];
            float sn2 = wsum(s * s);
            float sn = fmaxf(sqrtf(sn2), MINN);
            float th = tanhf(sn);
            float agg = th * s / sn;           // expmap0; |agg| == th
            if (th > MAXNRM) agg *= MAXNRM / th;
            float lin = liner[(size_t)grow * ODIM + lane];
            zl[r][lane] = agg;
            zl[r][64 + lane] = lin;            // same-wave LDS RAW, no barrier needed
            float d = biasnode[grow];
            const float* w = WN + lane;
#pragma unroll 8
            for (int f = 0; f < 128; ++f) d = fmaf(zl[r][f], w[f * 64], d);
            d = fmaxf(d, 0.0f);
            out_h[(size_t)grow * ODIM + lane] = d * agg + (1.0f - d) * lin;
        }
    }
    if (tid == 0)
        __hip_atomic_store(&cnt[blockIdx.x], 0u, __ATOMIC_RELAXED, __HIP_MEMORY_SCOPE_AGENT);
}

// ---- fallback: copy adj into second tuple output ----
__global__ void copy_adj(const float4* __restrict__ src, float4* __restrict__ dst, int n4) {
    for (int i = blockIdx.x * blockDim.x + threadIdx.x; i < n4; i += gridDim.x * blockDim.x)
        dst[i] = src[i];
}

extern "C" void kernel_launch(void* const* d_in, const int* in_sizes, int n_in,
                              void* d_out, int out_size, void* d_ws, size_t ws_size,
                              hipStream_t stream) {
    const float* x   = (const float*)d_in[0];
    const float* adj = (const float*)d_in[1];
    const float* Wd  = (const float*)d_in[2];
    const float* Wm  = (const float*)d_in[3];
    const float* bd  = (const float*)d_in[4];
    const float* bm  = (const float*)d_in[5];
    const float* wn  = (const float*)d_in[6];
    const float* bn  = (const float*)d_in[7];
    float* out = (float*)d_out;
    float* ws  = (float*)d_ws;

    const int WELEMS = ODIM * INDIM;          // 98944
    float* WtD   = ws;                        // 98944
    float* WtM   = ws + WELEMS;               // 98944
    float* hbD   = ws + 2 * WELEMS;           // 64
    float* hbM   = hbD + 64;                  // 64
    float* hb2   = hbM + 64;                  // 2
    float* liner = ws + 2 * WELEMS + 192;     // 98944
    float* xtan  = liner + WELEMS;            // 98944
    float* pnorm = xtan + WELEMS;             // 1546*8 = 12368
    unsigned* cnt = (unsigned*)(pnorm + 12368); // 2*194
    float* ws_end = (float*)(cnt + 2 * NRG);
    size_t used = (size_t)(ws_end - ws);
    // part: 1546*8*64 = 791552 floats, 64-float aligned
    size_t part_off = (used + 63) & ~(size_t)63;
    size_t need = (part_off + (size_t)NROWS * KS * 64) * sizeof(float);
    int fast = (ws_size >= need);
    float* part = fast ? (ws + part_off) : (out + WELEMS);

    unsigned* cntL = cnt;
    unsigned* cntA = cnt + NRG;

    prep_kernel<<<388, 256, 0, stream>>>(Wd, Wm, WtD, WtM, bd, bm, hbD, hbM, hb2, cnt);

    dim3 gA(NRG, KS);
    gemm_liner_fused<<<gA, 256, 0, stream>>>(x, WtD, WtM, hbD, hbM, hb2,
                                             part, pnorm, cntL, liner, xtan);
    gemm_agg_fused<<<gA, 256, 0, stream>>>(adj, xtan, liner, wn, bn,
                                           part, cntA, out, out + WELEMS, fast);
    if (!fast) {
        int n4 = (NROWS * NROWS) / 4;
        copy_adj<<<(n4 + 255) / 256, 256, 0, stream>>>((const float4*)adj,
                                                       (float4*)(out + WELEMS), n4);
    }
}

// Round 6
// 54.499 us; speedup vs baseline: 3.6014x; 3.5979x over previous
//
#include <hip/hip_runtime.h>
#include <math.h>

#define NROWS 1546
#define INDIM 1546
#define ODIM  64
#define NDRUG 1373
#define MINN  1e-15f
#define MAXNRM 0.996f   // (1 - 4e-3)/sqrt(c), c=1

#define KS   8          // K-splits (blocks in y)
#define CH   200        // 4-aligned K-chunk per split; last chunk = 1546-7*200 = 146
#define RSTR 200        // LDS row stride in floats (800B, 16B-aligned)
#define NRG  194        // row-groups of 8
#define QSTR 256        // packed quad stride: idx = (k>>2)*QSTR + col*4 + (k&3)
#define NQ   387        // ceil(1546/4) quads -> packed buffer = NQ*QSTR floats

__device__ __forceinline__ float artanh_(float x) {
    x = fminf(fmaxf(x, -1.0f + 1e-7f), 1.0f - 1e-7f);
    return 0.5f * (log1pf(x) - log1pf(-x));
}

__device__ __forceinline__ float wsum(float v) {
#pragma unroll
    for (int off = 32; off > 0; off >>= 1) v += __shfl_xor(v, off, 64);
    return v;
}

// ---- kernel 1: W[64][1546] -> packed Wq (both), bias prep (last block) ----
__global__ void prep_kernel(const float* __restrict__ Wd, const float* __restrict__ Wm,
                            float* __restrict__ WqD, float* __restrict__ WqM,
                            const float* __restrict__ bd, const float* __restrict__ bm,
                            float* __restrict__ hbD, float* __restrict__ hbM,
                            float* __restrict__ hb2) {
    if (blockIdx.x == gridDim.x - 1) {
        int tid = threadIdx.x;
        if (tid < 128) {
            int wave = tid >> 6, lane = tid & 63;
            const float* b = wave ? bm : bd;
            float v = b[lane];
            float un2 = wsum(v * v);
            float un = fmaxf(sqrtf(un2), MINN);
            float e = tanhf(un) * v / un;
            float en2 = wsum(e * e);
            float en = fmaxf(sqrtf(en2), MINN);
            float scl = (en > MAXNRM) ? (MAXNRM / en) : 1.0f;
            e *= scl;
            float* hb = wave ? hbM : hbD;
            hb[lane] = e;
            if (lane == 0) hb2[wave] = en2 * scl * scl;
        }
        return;
    }
    int nblk = gridDim.x - 1;
    int total = ODIM * INDIM;
    for (int i = blockIdx.x * blockDim.x + threadIdx.x; i < total; i += nblk * blockDim.x) {
        int o = i / INDIM;
        int k = i - o * INDIM;
        int qi = (k >> 2) * QSTR + o * 4 + (k & 3);
        WqD[qi] = Wd[i];
        WqM[qi] = Wm[i];
    }
}

// ---- kernel 2: split-K x@W^T with packed-quad W loads -> part, pnorm ----
__global__ __launch_bounds__(256) void gemmA_liner(
    const float* __restrict__ X, const float* __restrict__ WqD, const float* __restrict__ WqM,
    float* __restrict__ part, float* __restrict__ pnorm) {
    __shared__ __align__(16) float xs[8 * RSTR];
    int tid = threadIdx.x, wave = tid >> 6, lane = tid & 63;
    int row0 = blockIdx.x * 8;
    int kc = blockIdx.y;
    int k0 = kc * CH;               // multiple of 4
    int len = min(INDIM - k0, CH);  // 200 or 146 (even)

    {   // stage 8 rows x len as float2 (32 threads per row)
        int r = tid >> 5, c0 = tid & 31;
        int gr = min(row0 + r, NROWS - 1);
        const float2* src = (const float2*)(X + (size_t)gr * INDIM + k0);
        float2* dst = (float2*)&xs[r * RSTR];
        int len2 = len >> 1;
        for (int c = c0; c < len2; c += 32) dst[c] = src[c];
    }
    __syncthreads();

    int r0 = 2 * wave, r1 = r0 + 1;
    int g0 = row0 + r0, g1 = g0 + 1;

    {   // partial squared norms
        float p0 = 0.f, p1 = 0.f;
        for (int c = lane; c < len; c += 64) {
            float a = xs[r0 * RSTR + c]; p0 = fmaf(a, a, p0);
            float b = xs[r1 * RSTR + c]; p1 = fmaf(b, b, p1);
        }
        p0 = wsum(p0); p1 = wsum(p1);
        if (lane == 0) {
            if (g0 < NROWS) pnorm[g0 * KS + kc] = p0;
            if (g1 < NROWS) pnorm[g1 * KS + kc] = p1;
        }
    }

    const float* xa = xs + r0 * RSTR;
    const float* xb = xs + r1 * RSTR;
    int qbase = k0 >> 2;
    float acc0 = 0.f, acc1 = 0.f;
    bool u = (g0 < NDRUG) == (g1 < NDRUG);
    if (u) {
        const float* wq = ((g0 < NDRUG) ? WqD : WqM) + (size_t)qbase * QSTR + lane * 4;
        int kk = 0;
#pragma unroll 2
        for (; kk + 8 <= len; kk += 8) {
            float4 w0 = *(const float4*)(wq + (kk >> 2) * QSTR);
            float4 w1 = *(const float4*)(wq + ((kk >> 2) + 1) * QSTR);
            float4 a0 = *(const float4*)(xa + kk);
            float4 a1 = *(const float4*)(xa + kk + 4);
            float4 b0 = *(const float4*)(xb + kk);
            float4 b1 = *(const float4*)(xb + kk + 4);
            acc0 = fmaf(a0.x, w0.x, acc0); acc0 = fmaf(a0.y, w0.y, acc0);
            acc0 = fmaf(a0.z, w0.z, acc0); acc0 = fmaf(a0.w, w0.w, acc0);
            acc1 = fmaf(b0.x, w0.x, acc1); acc1 = fmaf(b0.y, w0.y, acc1);
            acc1 = fmaf(b0.z, w0.z, acc1); acc1 = fmaf(b0.w, w0.w, acc1);
            acc0 = fmaf(a1.x, w1.x, acc0); acc0 = fmaf(a1.y, w1.y, acc0);
            acc0 = fmaf(a1.z, w1.z, acc0); acc0 = fmaf(a1.w, w1.w, acc0);
            acc1 = fmaf(b1.x, w1.x, acc1); acc1 = fmaf(b1.y, w1.y, acc1);
            acc1 = fmaf(b1.z, w1.z, acc1); acc1 = fmaf(b1.w, w1.w, acc1);
        }
        for (; kk < len; ++kk) {    // tail (len=146: 2 iters)
            float w = wq[(kk >> 2) * QSTR + (kk & 3) - lane * 4 + lane * 4]; // same as below, keep simple:
            w = *(wq + (kk >> 2) * QSTR + (kk & 3));
            acc0 = fmaf(xa[kk], w, acc0);
            acc1 = fmaf(xb[kk], w, acc1);
        }
    } else {
        const float* wq0 = ((g0 < NDRUG) ? WqD : WqM) + (size_t)qbase * QSTR + lane * 4;
        const float* wq1 = ((g1 < NDRUG) ? WqD : WqM) + (size_t)qbase * QSTR + lane * 4;
        int kk = 0;
        for (; kk + 4 <= len; kk += 4) {
            float4 w0 = *(const float4*)(wq0 + (kk >> 2) * QSTR);
            float4 w1 = *(const float4*)(wq1 + (kk >> 2) * QSTR);
            float4 a = *(const float4*)(xa + kk);
            float4 b = *(const float4*)(xb + kk);
            acc0 = fmaf(a.x, w0.x, acc0); acc0 = fmaf(a.y, w0.y, acc0);
            acc0 = fmaf(a.z, w0.z, acc0); acc0 = fmaf(a.w, w0.w, acc0);
            acc1 = fmaf(b.x, w1.x, acc1); acc1 = fmaf(b.y, w1.y, acc1);
            acc1 = fmaf(b.z, w1.z, acc1); acc1 = fmaf(b.w, w1.w, acc1);
        }
        for (; kk < len; ++kk) {
            acc0 = fmaf(xa[kk], wq0[(kk >> 2) * QSTR + (kk & 3)], acc0);
            acc1 = fmaf(xb[kk], wq1[(kk >> 2) * QSTR + (kk & 3)], acc1);
        }
    }
    if (g0 < NROWS) part[(size_t)g0 * (KS * 64) + kc * 64 + lane] = acc0;
    if (g1 < NROWS) part[(size_t)g1 * (KS * 64) + kc * 64 + lane] = acc1;
}

// ---- kernel 3: reduce partials + hyperbolic epilogue -> liner (plain), xtq (packed) ----
__global__ __launch_bounds__(512) void linerB(
    const float* __restrict__ part, const float* __restrict__ pnorm,
    const float* __restrict__ hbD, const float* __restrict__ hbM, const float* __restrict__ hb2v,
    float* __restrict__ liner, float* __restrict__ xtq) {
    int wave = threadIdx.x >> 6, lane = threadIdx.x & 63;
    int grow = blockIdx.x * 8 + wave;
    if (grow >= NROWS) return;
    float mx = 0.f, xn2 = 0.f;
#pragma unroll
    for (int kc = 0; kc < KS; ++kc) mx += part[(size_t)grow * (KS * 64) + kc * 64 + lane];
#pragma unroll
    for (int kc = 0; kc < KS; ++kc) xn2 += pnorm[grow * KS + kc];

    float mxn2 = wsum(mx * mx);
    float xn = fmaxf(sqrtf(xn2), MINN);
    float mxn = fmaxf(sqrtf(mxn2), MINN);
    float g = mxn / xn * artanh_(xn);
    float t = tanhf(g);
    float res = t * mx / mxn;              // |res| == |t|
    float rn = fabsf(t);
    if (rn > MAXNRM) { res *= MAXNRM / rn; rn = MAXNRM; }
    const float* hb = (grow < NDRUG) ? hbD : hbM;
    float y = hb[lane];
    float y2 = hb2v[(grow < NDRUG) ? 0 : 1];
    float x2 = rn * rn;
    float xy = wsum(res * y);
    float num = (1.0f + 2.0f * xy + y2) * res + (1.0f - x2) * y;
    float den = 1.0f + 2.0f * xy + x2 * y2;
    float v = num / fmaxf(den, MINN);
    float v2 = wsum(v * v);
    float vn = fmaxf(sqrtf(v2), MINN);
    if (vn > MAXNRM) { v *= MAXNRM / vn; vn = MAXNRM; }
    float xt = artanh_(vn) / vn * v;       // logmap0
    liner[(size_t)grow * ODIM + lane] = v;
    xtq[(size_t)(grow >> 2) * QSTR + lane * 4 + (grow & 3)] = xt;  // packed for agg GEMM
}

// ---- kernel 4: split-K adj@xtan (packed loads) + fused adj copy -> part ----
__global__ __launch_bounds__(256) void gemmA_agg(
    const float* __restrict__ ADJ, const float* __restrict__ xtq,
    float* __restrict__ part, float* __restrict__ adj_out, int fuse_copy) {
    __shared__ __align__(16) float xs[8 * RSTR];
    int tid = threadIdx.x, wave = tid >> 6, lane = tid & 63;
    int row0 = blockIdx.x * 8;
    int kc = blockIdx.y;
    int k0 = kc * CH;
    int len = min(INDIM - k0, CH);

    {   // stage 8 rows x len as float2; optionally also write adj copy
        int r = tid >> 5, c0 = tid & 31;
        int gr0 = row0 + r;
        int gr = min(gr0, NROWS - 1);
        const float2* src = (const float2*)(ADJ + (size_t)gr * INDIM + k0);
        float2* dst = (float2*)&xs[r * RSTR];
        int len2 = len >> 1;
        if (fuse_copy && gr0 < NROWS) {
            float2* cp = (float2*)(adj_out + (size_t)gr0 * INDIM + k0);
            for (int c = c0; c < len2; c += 32) { float2 v = src[c]; dst[c] = v; cp[c] = v; }
        } else {
            for (int c = c0; c < len2; c += 32) dst[c] = src[c];
        }
    }
    __syncthreads();

    int r0 = 2 * wave, r1 = r0 + 1;
    int g0 = row0 + r0, g1 = g0 + 1;

    const float* xa = xs + r0 * RSTR;
    const float* xb = xs + r1 * RSTR;
    const float* wq = xtq + (size_t)(k0 >> 2) * QSTR + lane * 4;
    float acc0 = 0.f, acc1 = 0.f;
    int kk = 0;
#pragma unroll 2
    for (; kk + 8 <= len; kk += 8) {
        float4 w0 = *(const float4*)(wq + (kk >> 2) * QSTR);
        float4 w1 = *(const float4*)(wq + ((kk >> 2) + 1) * QSTR);
        float4 a0 = *(const float4*)(xa + kk);
        float4 a1 = *(const float4*)(xa + kk + 4);
        float4 b0 = *(const float4*)(xb + kk);
        float4 b1 = *(const float4*)(xb + kk + 4);
        acc0 = fmaf(a0.x, w0.x, acc0); acc0 = fmaf(a0.y, w0.y, acc0);
        acc0 = fmaf(a0.z, w0.z, acc0); acc0 = fmaf(a0.w, w0.w, acc0);
        acc1 = fmaf(b0.x, w0.x, acc1); acc1 = fmaf(b0.y, w0.y, acc1);
        acc1 = fmaf(b0.z, w0.z, acc1); acc1 = fmaf(b0.w, w0.w, acc1);
        acc0 = fmaf(a1.x, w1.x, acc0); acc0 = fmaf(a1.y, w1.y, acc0);
        acc0 = fmaf(a1.z, w1.z, acc0); acc0 = fmaf(a1.w, w1.w, acc0);
        acc1 = fmaf(b1.x, w1.x, acc1); acc1 = fmaf(b1.y, w1.y, acc1);
        acc1 = fmaf(b1.z, w1.z, acc1); acc1 = fmaf(b1.w, w1.w, acc1);
    }
    for (; kk < len; ++kk) {
        float w = wq[(kk >> 2) * QSTR + (kk & 3)];
        acc0 = fmaf(xa[kk], w, acc0);
        acc1 = fmaf(xb[kk], w, acc1);
    }
    if (g0 < NROWS) part[(size_t)g0 * (KS * 64) + kc * 64 + lane] = acc0;
    if (g1 < NROWS) part[(size_t)g1 * (KS * 64) + kc * 64 + lane] = acc1;
}

// ---- kernel 5: reduce partials + expmap0/proj + gated HypAct -> h ----
__global__ __launch_bounds__(512) void aggB(
    const float* __restrict__ part, const float* __restrict__ liner,
    const float* __restrict__ WN /*[128][64]*/, const float* __restrict__ biasnode,
    float* __restrict__ out_h) {
    __shared__ float zl[8][128];
    int wave = threadIdx.x >> 6, lane = threadIdx.x & 63;
    int grow = blockIdx.x * 8 + wave;
    if (grow >= NROWS) return;
    float s = 0.f;
#pragma unroll
    for (int kc = 0; kc < KS; ++kc) s += part[(size_t)grow * (KS * 64) + kc * 64 + lane];
    float sn2 = wsum(s * s);
    float sn = fmaxf(sqrtf(sn2), MINN);
    float th = tanhf(sn);
    float agg = th * s / sn;               // expmap0; |agg| == th
    if (th > MAXNRM) agg *= MAXNRM / th;
    float lin = liner[(size_t)grow * ODIM + lane];
    zl[wave][lane] = agg;
    zl[wave][64 + lane] = lin;             // same-wave LDS RAW, no barrier needed
    float d = biasnode[grow];
    const float* w = WN + lane;
#pragma unroll 8
    for (int f = 0; f < 128; ++f) d = fmaf(zl[wave][f], w[f * 64], d);
    d = fmaxf(d, 0.0f);
    out_h[(size_t)grow * ODIM + lane] = d * agg + (1.0f - d) * lin;
}

// ---- fallback: copy adj into second tuple output ----
__global__ void copy_adj(const float4* __restrict__ src, float4* __restrict__ dst, int n4) {
    for (int i = blockIdx.x * blockDim.x + threadIdx.x; i < n4; i += gridDim.x * blockDim.x)
        dst[i] = src[i];
}

extern "C" void kernel_launch(void* const* d_in, const int* in_sizes, int n_in,
                              void* d_out, int out_size, void* d_ws, size_t ws_size,
                              hipStream_t stream) {
    const float* x   = (const float*)d_in[0];
    const float* adj = (const float*)d_in[1];
    const float* Wd  = (const float*)d_in[2];
    const float* Wm  = (const float*)d_in[3];
    const float* bd  = (const float*)d_in[4];
    const float* bm  = (const float*)d_in[5];
    const float* wn  = (const float*)d_in[6];
    const float* bn  = (const float*)d_in[7];
    float* out = (float*)d_out;
    float* ws  = (float*)d_ws;

    const int WELEMS = ODIM * INDIM;          // 98944
    const int QELEMS = NQ * QSTR;             // 99072
    float* WqD   = ws;                        // 99072
    float* WqM   = WqD + QELEMS;              // 99072
    float* hbD   = WqM + QELEMS;              // 64
    float* hbM   = hbD + 64;                  // 64
    float* hb2   = hbM + 64;                  // 2 (+pad to 192)
    float* liner = hbD + 192;                 // 98944
    float* xtq   = liner + WELEMS;            // 99072 (packed)
    float* pnorm = xtq + QELEMS;              // 1546*8 = 12368
    float* ws_end = pnorm + 12368;
    size_t used = (size_t)(ws_end - ws);
    size_t part_off = (used + 63) & ~(size_t)63;
    size_t need = (part_off + (size_t)NROWS * KS * 64) * sizeof(float);
    int fast = (ws_size >= need);
    float* part = fast ? (ws + part_off) : (out + WELEMS);

    prep_kernel<<<388, 256, 0, stream>>>(Wd, Wm, WqD, WqM, bd, bm, hbD, hbM, hb2);

    dim3 gA(NRG, KS);
    gemmA_liner<<<gA, 256, 0, stream>>>(x, WqD, WqM, part, pnorm);
    linerB<<<NRG, 512, 0, stream>>>(part, pnorm, hbD, hbM, hb2, liner, xtq);
    gemmA_agg<<<gA, 256, 0, stream>>>(adj, xtq, part, out + WELEMS, fast);
    aggB<<<NRG, 512, 0, stream>>>(part, liner, wn, bn, out);
    if (!fast) {
        int n4 = (NROWS * NROWS) / 4;
        copy_adj<<<(n4 + 255) / 256, 256, 0, stream>>>((const float4*)adj,
                                                       (float4*)(out + WELEMS), n4);
    }
}